// Round 10
// baseline (215.217 us; speedup 1.0000x reference)
//
#include <hip/hip_runtime.h>
#include <hip/hip_bf16.h>

#define T_LEN 2048
#define HID 2048
#define NH 16
#define NKV 4
#define HD 128
#define QKV_COLS 3072   // (16 + 2*4) * 128

typedef __attribute__((ext_vector_type(8))) short bf16x8;
typedef __attribute__((ext_vector_type(4))) float f32x4;

static __device__ __forceinline__ ushort f2bf(float f) {
  __hip_bfloat16 h = __float2bfloat16(f);
  return *reinterpret_cast<ushort*>(&h);
}
static __device__ __forceinline__ float bf2f(ushort u) {
  union { unsigned int i; float f; } v;
  v.i = ((unsigned int)u) << 16;
  return v.f;
}

// async global->LDS DMA, 16 bytes per lane (lane-linear LDS destination)
static __device__ __forceinline__ void async_copy16(const ushort* g, ushort* l) {
  __builtin_amdgcn_global_load_lds(
      (const __attribute__((address_space(1))) unsigned int*)g,
      (__attribute__((address_space(3))) unsigned int*)l, 16, 0, 0);
}

// ---------------------------------------------------------------------------
// cast fp32 -> bf16
// ---------------------------------------------------------------------------
__global__ __launch_bounds__(256) void cast_f32_bf16(
    const float* __restrict__ x, ushort* __restrict__ y, int n) {
  int idx = (blockIdx.x * 256 + threadIdx.x) * 4;
  if (idx < n) {
    float4 v = *(const float4*)(x + idx);
    ushort4 o;
    o.x = f2bf(v.x); o.y = f2bf(v.y); o.z = f2bf(v.z); o.w = f2bf(v.w);
    *(ushort4*)(y + idx) = o;
  }
}

// ---------------------------------------------------------------------------
// W [K][N] fp32  ->  WT [N][K] bf16
// ---------------------------------------------------------------------------
__global__ __launch_bounds__(256) void transpose_cast(
    const float* __restrict__ W, ushort* __restrict__ WT, int K, int N) {
  __shared__ float t[64][65];
  const int bk = blockIdx.x * 64, bn = blockIdx.y * 64;
  const int tid = threadIdx.x;
  const int c = tid & 63;
#pragma unroll
  for (int i = 0; i < 16; ++i) {
    int r = (tid >> 6) + i * 4;
    t[r][c] = W[(size_t)(bk + r) * N + bn + c];
  }
  __syncthreads();
#pragma unroll
  for (int i = 0; i < 16; ++i) {
    int r = (tid >> 6) + i * 4;
    WT[(size_t)(bn + r) * K + bk + c] = f2bf(t[c][r]);
  }
}

// ---------------------------------------------------------------------------
// RoPE cos/sin table: tbl[t][j] = {cos, sin}(positions[t] * 1e6^(-2j/128))
// ---------------------------------------------------------------------------
__global__ __launch_bounds__(64) void rope_table(
    float2* __restrict__ tbl, const int* __restrict__ positions) {
  const int t = blockIdx.x, j = threadIdx.x;
  double inv_freq = pow(1000000.0, -(double)(2 * j) / 128.0);
  double ang = (double)positions[t] * inv_freq;
  double s, c;
  sincos(ang, &s, &c);
  tbl[(size_t)t * 64 + j] = make_float2((float)c, (float)s);
}

// ---------------------------------------------------------------------------
// XCD-aware block decode. 1-D grid of (N/128)*(M/64) blocks; xcd = blk & 7
// (dispatch round-robins workgroups over the 8 XCDs). Each XCD owns
// (N/128)/8 full B-column panels x all M-tiles, so B-tile re-reads hit its
// private 4 MiB L2 instead of the Infinity Cache.
// ---------------------------------------------------------------------------
static __device__ __forceinline__ void xcd_decode(int M, int N, int& bm, int& bn) {
  const int mt = M >> 6;                 // # m-tiles
  const int ppx = (N >> 7) >> 3;         // B panels per XCD
  const int b = blockIdx.x;
  const int xcd = b & 7;
  const int idx = b >> 3;                // 0 .. mt*ppx-1
  bn = (xcd * ppx + idx / mt) << 7;
  bm = (idx % mt) << 6;
}

// ---------------------------------------------------------------------------
// bf16 MFMA GEMM-BT: C[M][N] = A[M][K] @ BT[N][K]^T, fp32 accum.
// Tile 64(M)x128(N), BK=64, 256 thr = 4 waves (wave tile 32x64).
// global_load_lds staging into XOR-swizzled LDS cells. XCD-swizzled grid.
// ---------------------------------------------------------------------------
template <bool OUT_BF16>
__global__ __launch_bounds__(256, 5) void gemm_bt(
    const ushort* __restrict__ A, const ushort* __restrict__ BT,
    void* __restrict__ C, int M, int N, int K) {
  __shared__ __align__(16) ushort lds[1536 * 8];   // A: cells 0..511, B: 512..1535
  const int tid = threadIdx.x;
  int bm, bn;
  xcd_decode(M, N, bm, bn);
  const int wave = tid >> 6, lane = tid & 63;
  const int lr = lane & 15, lq = lane >> 4;
  const int wm = (wave & 1) * 32, wn = (wave >> 1) * 64;

  f32x4 acc[2][4];
#pragma unroll
  for (int i = 0; i < 2; ++i)
#pragma unroll
    for (int j = 0; j < 4; ++j) {
      acc[i][j][0] = 0.f; acc[i][j][1] = 0.f;
      acc[i][j][2] = 0.f; acc[i][j][3] = 0.f;
    }

  for (int k0 = 0; k0 < K; k0 += 64) {
#pragma unroll
    for (int it = 0; it < 2; ++it) {
      int c = it * 256 + tid;
      int row = c >> 3, sl = c & 7, kc = sl ^ (row & 7);
      async_copy16(A + (size_t)(bm + row) * K + k0 + kc * 8, &lds[c * 8]);
    }
#pragma unroll
    for (int it = 0; it < 4; ++it) {
      int c = it * 256 + tid;
      int row = c >> 3, sl = c & 7, kc = sl ^ (row & 7);
      async_copy16(BT + (size_t)(bn + row) * K + k0 + kc * 8,
                   &lds[(512 + c) * 8]);
    }
    __syncthreads();

#pragma unroll
    for (int ks = 0; ks < 2; ++ks) {
      bf16x8 af[2], bfr[4];
#pragma unroll
      for (int mi = 0; mi < 2; ++mi) {
        int row = wm + mi * 16 + lr, kc = ks * 4 + lq;
        af[mi] = *(const bf16x8*)&lds[(row * 8 + (kc ^ (row & 7))) * 8];
      }
#pragma unroll
      for (int ni = 0; ni < 4; ++ni) {
        int row = wn + ni * 16 + lr, kc = ks * 4 + lq;
        bfr[ni] = *(const bf16x8*)&lds[(512 + row * 8 + (kc ^ (row & 7))) * 8];
      }
#pragma unroll
      for (int mi = 0; mi < 2; ++mi)
#pragma unroll
        for (int ni = 0; ni < 4; ++ni)
          acc[mi][ni] = __builtin_amdgcn_mfma_f32_16x16x32_bf16(
              af[mi], bfr[ni], acc[mi][ni], 0, 0, 0);
    }
    __syncthreads();
  }

#pragma unroll
  for (int mi = 0; mi < 2; ++mi)
#pragma unroll
    for (int ni = 0; ni < 4; ++ni)
#pragma unroll
      for (int r = 0; r < 4; ++r) {
        size_t row = bm + wm + mi * 16 + lq * 4 + r;
        size_t col = bn + wn + ni * 16 + lr;
        if (OUT_BF16)
          ((ushort*)C)[row * N + col] = f2bf(acc[mi][ni][r]);
        else
          ((float*)C)[row * N + col] = acc[mi][ni][r];
      }
}

// ---------------------------------------------------------------------------
// gemm1 with fused RoPE epilogue (N-tile == one head). XCD-swizzled grid.
// ---------------------------------------------------------------------------
__global__ __launch_bounds__(256, 5) void gemm_qkv(
    const ushort* __restrict__ A, const ushort* __restrict__ BT,
    ushort* __restrict__ qkvb, const float2* __restrict__ tbl,
    int M, int N, int K) {
  __shared__ __align__(16) ushort lds[1536 * 8];
  const int tid = threadIdx.x;
  int bm, bn;
  xcd_decode(M, N, bm, bn);
  const int wave = tid >> 6, lane = tid & 63;
  const int lr = lane & 15, lq = lane >> 4;
  const int wm = (wave & 1) * 32, wn = (wave >> 1) * 64;

  f32x4 acc[2][4];
#pragma unroll
  for (int i = 0; i < 2; ++i)
#pragma unroll
    for (int j = 0; j < 4; ++j) {
      acc[i][j][0] = 0.f; acc[i][j][1] = 0.f;
      acc[i][j][2] = 0.f; acc[i][j][3] = 0.f;
    }

  for (int k0 = 0; k0 < K; k0 += 64) {
#pragma unroll
    for (int it = 0; it < 2; ++it) {
      int c = it * 256 + tid;
      int row = c >> 3, sl = c & 7, kc = sl ^ (row & 7);
      async_copy16(A + (size_t)(bm + row) * K + k0 + kc * 8, &lds[c * 8]);
    }
#pragma unroll
    for (int it = 0; it < 4; ++it) {
      int c = it * 256 + tid;
      int row = c >> 3, sl = c & 7, kc = sl ^ (row & 7);
      async_copy16(BT + (size_t)(bn + row) * K + k0 + kc * 8,
                   &lds[(512 + c) * 8]);
    }
    __syncthreads();

#pragma unroll
    for (int ks = 0; ks < 2; ++ks) {
      bf16x8 af[2], bfr[4];
#pragma unroll
      for (int mi = 0; mi < 2; ++mi) {
        int row = wm + mi * 16 + lr, kc = ks * 4 + lq;
        af[mi] = *(const bf16x8*)&lds[(row * 8 + (kc ^ (row & 7))) * 8];
      }
#pragma unroll
      for (int ni = 0; ni < 4; ++ni) {
        int row = wn + ni * 16 + lr, kc = ks * 4 + lq;
        bfr[ni] = *(const bf16x8*)&lds[(512 + row * 8 + (kc ^ (row & 7))) * 8];
      }
#pragma unroll
      for (int mi = 0; mi < 2; ++mi)
#pragma unroll
        for (int ni = 0; ni < 4; ++ni)
          acc[mi][ni] = __builtin_amdgcn_mfma_f32_16x16x32_bf16(
              af[mi], bfr[ni], acc[mi][ni], 0, 0, 0);
    }
    __syncthreads();
  }

  const int head = bn >> 7;
  if (head < 20) {
    // ---- q/k head: rope via LDS round trip (64 rows x 130 pitch, bf16)
    ushort* ep = lds;   // 64*130 = 8320 ushorts <= 12288
#pragma unroll
    for (int mi = 0; mi < 2; ++mi)
#pragma unroll
      for (int ni = 0; ni < 4; ++ni)
#pragma unroll
        for (int r = 0; r < 4; ++r)
          ep[(wm + mi * 16 + lq * 4 + r) * 130 + wn + ni * 16 + lr] =
              f2bf(acc[mi][ni][r]);
    __syncthreads();

    const float qs = (head < NH) ? 0.08838834764831845f : 1.0f;
#pragma unroll
    for (int it = 0; it < 16; ++it) {
      int idx = it * 256 + tid;        // 64 rows x 64 pairs
      int row = idx >> 6, j = idx & 63;
      float x1 = bf2f(ep[row * 130 + j]);
      float x2 = bf2f(ep[row * 130 + 64 + j]);
      float2 cs = tbl[(size_t)(bm + row) * 64 + j];
      qkvb[(size_t)(bm + row) * QKV_COLS + bn + j] =
          f2bf((x1 * cs.x - x2 * cs.y) * qs);
      qkvb[(size_t)(bm + row) * QKV_COLS + bn + 64 + j] =
          f2bf((x2 * cs.x + x1 * cs.y) * qs);
    }
  } else {
    // ---- v head: plain bf16 write
#pragma unroll
    for (int mi = 0; mi < 2; ++mi)
#pragma unroll
      for (int ni = 0; ni < 4; ++ni)
#pragma unroll
        for (int r = 0; r < 4; ++r) {
          size_t row = bm + wm + mi * 16 + lq * 4 + r;
          size_t col = bn + wn + ni * 16 + lr;
          qkvb[row * QKV_COLS + col] = f2bf(acc[mi][ni][r]);
        }
  }
}

// ---------------------------------------------------------------------------
// Repack V (LDS-tiled transpose): vt[vd][t] = qkv[t][2560 + vd]
// ---------------------------------------------------------------------------
__global__ __launch_bounds__(256) void repack_vt(
    const ushort* __restrict__ qkv, ushort* __restrict__ vt) {
  __shared__ ushort tile[64][65];
  const int bt = blockIdx.x * 64;
  const int bv = blockIdx.y * 64;
  const int tid = threadIdx.x;
  const int c = tid & 63, r0 = tid >> 6;
#pragma unroll
  for (int i = 0; i < 16; ++i) {
    int r = r0 + i * 4;
    tile[r][c] = qkv[(size_t)(bt + r) * QKV_COLS + 2560 + bv + c];
  }
  __syncthreads();
#pragma unroll
  for (int i = 0; i < 16; ++i) {
    int r = r0 + i * 4;
    vt[(size_t)(bv + r) * T_LEN + bt + c] = tile[c][r];
  }
}

// ---------------------------------------------------------------------------
// Flash attention v4 (r8, unchanged): m=0 softmax, 2x2 wave QK split,
// register Q, DMA-staged swizzled K/V, PV d-split, split-K 768 blocks.
// ---------------------------------------------------------------------------
__global__ __launch_bounds__(256, 3) void attn_mfma(
    const ushort* __restrict__ qkv, const ushort* __restrict__ vt,
    ushort* __restrict__ o, ushort* __restrict__ partials,
    float* __restrict__ ml) {
  int qt, h, k_begin, k_end, slot = -1;
  {
    const int i = blockIdx.x;
    if (i < 512) {
      qt = 31 - (i >> 5);
      const int rem = i & 31;
      h = rem >> 1;
      const int chunk = rem & 1;
      const int n = qt + 1, half = n >> 1;
      k_begin = chunk ? half : 0;
      k_end = chunk ? n : half;
      slot = ((qt - 16) * 16 + h) * 2 + chunk;
    } else {
      const int j = i - 512;
      qt = 15 - (j >> 4);
      h = j & 15;
      k_begin = 0;
      k_end = qt + 1;
    }
  }
  const int kh = h >> 2;
  const int tid = threadIdx.x;
  const int wave = tid >> 6, lane = tid & 63;
  const int lr = lane & 15, lq = lane >> 4;
  const int wq = wave >> 1, ws = wave & 1;

  __shared__ __align__(16) ushort KsL[1024 * 8];
  __shared__ __align__(16) ushort VtsL[1024 * 8];
  __shared__ __align__(16) ushort Ps[8 * 67 * 8];
  __shared__ float l_sh[64][2];

  bf16x8 qf[2][4];
  {
    const ushort* qbase =
        qkv + (size_t)(qt * 64 + wq * 32 + lr) * QKV_COLS + h * HD + lq * 8;
#pragma unroll
    for (int mi = 0; mi < 2; ++mi)
#pragma unroll
      for (int kk = 0; kk < 4; ++kk)
        qf[mi][kk] = *(const bf16x8*)(qbase + (size_t)mi * 16 * QKV_COLS + kk * 32);
  }

  float l_part[2][4];
#pragma unroll
  for (int mi = 0; mi < 2; ++mi)
#pragma unroll
    for (int r = 0; r < 4; ++r) l_part[mi][r] = 0.f;
  f32x4 o_acc[4][2];
#pragma unroll
  for (int qi = 0; qi < 4; ++qi)
#pragma unroll
    for (int di = 0; di < 2; ++di) {
      o_acc[qi][di][0] = 0.f; o_acc[qi][di][1] = 0.f;
      o_acc[qi][di][2] = 0.f; o_acc[qi][di][3] = 0.f;
    }

  for (int kt = k_begin; kt < k_end; ++kt) {
    __syncthreads();

    {
      const ushort* kbase = qkv + 2048 + kh * HD;
#pragma unroll
      for (int it = 0; it < 4; ++it) {
        int c = it * 256 + tid;
        int s = c >> 4, sl = c & 15, dg = sl ^ (s & 15);
        async_copy16(kbase + (size_t)(kt * 64 + s) * QKV_COLS + dg * 8,
                     &KsL[c * 8]);
      }
    }
    {
      const ushort* vbase = vt + (size_t)(kh * HD) * T_LEN + kt * 64;
#pragma unroll
      for (int it = 0; it < 4; ++it) {
        int c = it * 256 + tid;
        int d = c >> 3, sl = c & 7, sc = sl ^ (d & 7);
        async_copy16(vbase + (size_t)d * T_LEN + sc * 8, &VtsL[c * 8]);
      }
    }
    __syncthreads();

    f32x4 s_acc[2][2];
#pragma unroll
    for (int mi = 0; mi < 2; ++mi)
#pragma unroll
      for (int ni = 0; ni < 2; ++ni) {
        s_acc[mi][ni][0] = 0.f; s_acc[mi][ni][1] = 0.f;
        s_acc[mi][ni][2] = 0.f; s_acc[mi][ni][3] = 0.f;
      }
#pragma unroll
    for (int kk = 0; kk < 4; ++kk) {
      bf16x8 kf[2];
#pragma unroll
      for (int ni = 0; ni < 2; ++ni) {
        int s = ws * 32 + ni * 16 + lr;
        kf[ni] = *(const bf16x8*)&KsL[(s * 16 + ((kk * 4 + lq) ^ (s & 15))) * 8];
      }
#pragma unroll
      for (int mi = 0; mi < 2; ++mi)
#pragma unroll
        for (int ni = 0; ni < 2; ++ni)
          s_acc[mi][ni] = __builtin_amdgcn_mfma_f32_16x16x32_bf16(
              qf[mi][kk], kf[ni], s_acc[mi][ni], 0, 0, 0);
    }

    if (kt == qt) {
#pragma unroll
      for (int mi = 0; mi < 2; ++mi)
#pragma unroll
        for (int ni = 0; ni < 2; ++ni)
#pragma unroll
          for (int r = 0; r < 4; ++r)
            if (ws * 32 + ni * 16 + lr > wq * 32 + mi * 16 + lq * 4 + r)
              s_acc[mi][ni][r] = -1e30f;
    }

#pragma unroll
    for (int mi = 0; mi < 2; ++mi)
#pragma unroll
      for (int ni = 0; ni < 2; ++ni)
#pragma unroll
        for (int r = 0; r < 4; ++r) {
          float p = __expf(s_acc[mi][ni][r]);
          l_part[mi][r] += p;
          int s = ws * 32 + ni * 16 + lr;
          int q = wq * 32 + mi * 16 + lq * 4 + r;
          Ps[((s >> 3) * 67 + q) * 8 + (s & 7)] = f2bf(p);
        }
    __syncthreads();

#pragma unroll
    for (int ss = 0; ss < 2; ++ss) {
      bf16x8 vf[2];
#pragma unroll
      for (int di = 0; di < 2; ++di) {
        int d = wave * 32 + di * 16 + lr, sc = ss * 4 + lq;
        vf[di] = *(const bf16x8*)&VtsL[(d * 8 + (sc ^ (d & 7))) * 8];
      }
#pragma unroll
      for (int qi = 0; qi < 4; ++qi) {
        bf16x8 pf = *(const bf16x8*)&Ps[((ss * 4 + lq) * 67 + qi * 16 + lr) * 8];
#pragma unroll
        for (int di = 0; di < 2; ++di)
          o_acc[qi][di] = __builtin_amdgcn_mfma_f32_16x16x32_bf16(
              pf, vf[di], o_acc[qi][di], 0, 0, 0);
      }
    }
  }

#pragma unroll
  for (int mi = 0; mi < 2; ++mi)
#pragma unroll
    for (int r = 0; r < 4; ++r) {
      float v = l_part[mi][r];
#pragma unroll
      for (int off = 1; off < 16; off <<= 1) v += __shfl_xor(v, off, 16);
      l_part[mi][r] = v;
    }
  if (lr == 0) {
#pragma unroll
    for (int mi = 0; mi < 2; ++mi)
#pragma unroll
      for (int r = 0; r < 4; ++r)
        l_sh[wq * 32 + mi * 16 + lq * 4 + r][ws] = l_part[mi][r];
  }
  __syncthreads();

  if (slot < 0) {
    ushort* ob = o + (size_t)(qt * 64) * (NH * HD) + h * HD + wave * 32;
#pragma unroll
    for (int qi = 0; qi < 4; ++qi)
#pragma unroll
      for (int r = 0; r < 4; ++r) {
        int q = qi * 16 + lq * 4 + r;
        float inv = 1.f / (l_sh[q][0] + l_sh[q][1]);
#pragma unroll
        for (int di = 0; di < 2; ++di)
          ob[(size_t)q * (NH * HD) + di * 16 + lr] =
              f2bf(o_acc[qi][di][r] * inv);
      }
  } else {
    ushort* pb = partials + (size_t)slot * 64 * HD + wave * 32;
#pragma unroll
    for (int qi = 0; qi < 4; ++qi)
#pragma unroll
      for (int r = 0; r < 4; ++r) {
        int q = qi * 16 + lq * 4 + r;
#pragma unroll
        for (int di = 0; di < 2; ++di)
          pb[(size_t)q * HD + di * 16 + lr] = f2bf(o_acc[qi][di][r]);
      }
    if (tid < 64) ml[(size_t)slot * 64 + tid] = l_sh[tid][0] + l_sh[tid][1];
  }
}

// ---------------------------------------------------------------------------
// Combine the two key-range chunks for qt >= 16 (m=0: plain sum).
// ---------------------------------------------------------------------------
__global__ __launch_bounds__(256) void attn_reduce(
    const ushort* __restrict__ partials, const float* __restrict__ ml,
    ushort* __restrict__ o) {
  const int bi = blockIdx.x;
  const int qt = 16 + (bi >> 4), h = bi & 15;
  const int s0 = ((qt - 16) * 16 + h) * 2;
  const int tid = threadIdx.x;
  const int row = tid >> 2;
  const int dq = (tid & 3) * 32;

  float l0 = ml[(size_t)s0 * 64 + row];
  float l1 = ml[(size_t)(s0 + 1) * 64 + row];
  float inv = 1.f / (l0 + l1);

  const ushort* p0 = partials + ((size_t)s0 * 64 + row) * HD + dq;
  const ushort* p1 = partials + ((size_t)(s0 + 1) * 64 + row) * HD + dq;
  ushort* ob = o + (size_t)(qt * 64 + row) * (NH * HD) + h * HD + dq;
#pragma unroll
  for (int k = 0; k < 32; ++k)
    ob[k] = f2bf((bf2f(p0[k]) + bf2f(p1[k])) * inv);
}

// ---------------------------------------------------------------------------
extern "C" void kernel_launch(void* const* d_in, const int* in_sizes, int n_in,
                              void* d_out, int out_size, void* d_ws,
                              size_t ws_size, hipStream_t stream) {
  const float* hidden = (const float*)d_in[0];
  const float* w_qkv  = (const float*)d_in[1];
  const float* w_o    = (const float*)d_in[2];
  const int* positions = (const int*)d_in[3];
  float* out = (float*)d_out;

  ushort* ws = (ushort*)d_ws;
  ushort* hb    = ws;                    // 2048*2048  (dead after gemm1 -> ob)
  ushort* wqkvT = ws + 4194304;          // 3072*2048  (-> partials -> woT)
  ushort* qkvb  = wqkvT + 6291456;       // 2048*3072
  ushort* vtb   = qkvb + 6291456;        // 512*2048
  float*  mlb   = (float*)(vtb + 1048576);        // 512*64 fp32 = 128 KB
  float2* tbl   = (float2*)(mlb + 32768);         // 2048*64 float2 = 1 MB
  ushort* ob       = hb;
  ushort* partials = wqkvT;
  ushort* woT      = wqkvT;
  // peak usage ~36.9 MB (round-2 proved ws >= 41.9 MB)

  cast_f32_bf16<<<4096, 256, 0, stream>>>(hidden, hb, HID * T_LEN);
  transpose_cast<<<dim3(HID / 64, QKV_COLS / 64), 256, 0, stream>>>(
      w_qkv, wqkvT, HID, QKV_COLS);
  rope_table<<<T_LEN, 64, 0, stream>>>(tbl, positions);

  // 1-D XCD-swizzled grid: (N/128)*(M/64) blocks
  gemm_qkv<<<(QKV_COLS / 128) * (T_LEN / 64), 256, 0, stream>>>(
      hb, wqkvT, qkvb, tbl, T_LEN, QKV_COLS, HID);

  repack_vt<<<dim3(T_LEN / 64, (NKV * HD) / 64), 256, 0, stream>>>(qkvb, vtb);

  attn_mfma<<<768, 256, 0, stream>>>(qkvb, vtb, ob, partials, mlb);
  attn_reduce<<<256, 256, 0, stream>>>(partials, mlb, ob);

  transpose_cast<<<dim3(HID / 64, HID / 64), 256, 0, stream>>>(
      w_o, woT, HID, HID);

  gemm_bt<false><<<(HID / 128) * (T_LEN / 64), 256, 0, stream>>>(
      ob, woT, out, T_LEN, HID, NH * HD);
}